// Round 4
// baseline (469.368 us; speedup 1.0000x reference)
//
#include <hip/hip_runtime.h>
#include <hip/hip_fp16.h>

#define N_NODES 50000
#define N_EDGES 1600000
#define IN_DIM  128
#define OUT_DIM 32
#define HEADS   4
#define EDGE_DIM 16

#define GEMM_BLOCKS ((N_NODES + 31) / 32)        // 1563
#define HIST_BLOCKS 1024

// K1: fused  [gemm tiles | edge-dst histogram]  via block partition.
// gemm epilogue: writes h2t (fp16, [n][d][head]) and accumulates
// a_src/a_dst via block-local atomics (replaces k_att).
__global__ __launch_bounds__(256) void k_main1(
    const float* __restrict__ x, const float* __restrict__ Wl,
    const float* __restrict__ att_src, const float* __restrict__ att_dst,
    const int* __restrict__ ei,
    __half* __restrict__ h2t, float* __restrict__ a_src,
    float* __restrict__ a_dst, unsigned int* __restrict__ cnt) {
  if (blockIdx.x >= GEMM_BLOCKS) {
    // ---- histogram role ----
    int base = (blockIdx.x - GEMM_BLOCKS) * 256 + threadIdx.x;
    for (int e = base; e < N_EDGES; e += HIST_BLOCKS * 256)
      atomicAdd(&cnt[ei[N_EDGES + e]], 1u);
    return;
  }
  // ---- gemm role ----
  __shared__ float Wt[IN_DIM][68];
  __shared__ float xs[32][132];
  __shared__ float attS[IN_DIM], attD[IN_DIM];
  const int t = threadIdx.x;
  const int n0 = blockIdx.x * 32;

  if (t < IN_DIM) { attS[t] = att_src[t]; attD[t] = att_dst[t]; }

  for (int it = 0; it < 16; ++it) {
    int idx = it * 256 + t;
    int node = idx >> 7, i = idx & 127;
    int n = n0 + node;
    xs[node][i] = (n < N_NODES) ? x[(size_t)n * IN_DIM + i] : 0.f;
  }

  const int tx = t & 15, ty = t >> 4;
  const int na = n0 + 2 * ty, nb = na + 1;

  for (int p = 0; p < 2; ++p) {
    __syncthreads();
    for (int it = 0; it < 32; ++it) {
      int idx = it * 256 + t;
      int kg = (idx >> 7) + p * 64, i = idx & 127;
      Wt[i][kg - p * 64] = Wl[(size_t)kg * IN_DIM + i];
    }
    __syncthreads();

    float4 acc0 = {0.f,0.f,0.f,0.f}, acc1 = {0.f,0.f,0.f,0.f};
    for (int i4 = 0; i4 < IN_DIM; i4 += 4) {
      float4 xa = *(const float4*)&xs[2*ty][i4];
      float4 xb = *(const float4*)&xs[2*ty+1][i4];
      const float* xap = (const float*)&xa;
      const float* xbp = (const float*)&xb;
      #pragma unroll
      for (int ii = 0; ii < 4; ++ii) {
        float4 wv = *(const float4*)&Wt[i4+ii][tx*4];
        float a = xap[ii], b = xbp[ii];
        acc0.x += a*wv.x; acc0.y += a*wv.y; acc0.z += a*wv.z; acc0.w += a*wv.w;
        acc1.x += b*wv.x; acc1.y += b*wv.y; acc1.z += b*wv.z; acc1.w += b*wv.w;
      }
    }
    const int k = p*64 + tx*4;
    const int hd = k >> 5, d0 = k & 31;
    const float* ap = (const float*)&acc0;
    const float* bp = (const float*)&acc1;
    float sa = ap[0]*attS[k] + ap[1]*attS[k+1] + ap[2]*attS[k+2] + ap[3]*attS[k+3];
    float da = ap[0]*attD[k] + ap[1]*attD[k+1] + ap[2]*attD[k+2] + ap[3]*attD[k+3];
    float sb = bp[0]*attS[k] + bp[1]*attS[k+1] + bp[2]*attS[k+2] + bp[3]*attS[k+3];
    float db = bp[0]*attD[k] + bp[1]*attD[k+1] + bp[2]*attD[k+2] + bp[3]*attD[k+3];
    if (na < N_NODES) {
      #pragma unroll
      for (int j = 0; j < 4; ++j)
        h2t[(size_t)na*IN_DIM + (d0+j)*4 + hd] = __float2half(ap[j]);
      atomicAdd(&a_src[na*4 + hd], sa);
      atomicAdd(&a_dst[na*4 + hd], da);
    }
    if (nb < N_NODES) {
      #pragma unroll
      for (int j = 0; j < 4; ++j)
        h2t[(size_t)nb*IN_DIM + (d0+j)*4 + hd] = __float2half(bp[j]);
      atomicAdd(&a_src[nb*4 + hd], sb);
      atomicAdd(&a_dst[nb*4 + hd], db);
    }
  }
}

// K4a: per-block exclusive scan (1024 entries/block) + block totals
__global__ __launch_bounds__(1024) void k_scan1(
    const unsigned int* __restrict__ cnt, unsigned int* __restrict__ start,
    unsigned int* __restrict__ bsum) {
  __shared__ unsigned int s[1024];
  const int t = threadIdx.x;
  const int gid = blockIdx.x * 1024 + t;
  unsigned int v = (gid < N_NODES) ? cnt[gid] : 0u;
  s[t] = v; __syncthreads();
  for (int off = 1; off < 1024; off <<= 1) {
    unsigned int u = (t >= off) ? s[t - off] : 0u;
    __syncthreads();
    s[t] += u;
    __syncthreads();
  }
  if (gid < N_NODES) start[gid] = s[t] - v;
  if (t == 1023) bsum[blockIdx.x] = s[t];
}

// K4b: scan the 49 block totals (single wave)
__global__ __launch_bounds__(64) void k_scan2(
    const unsigned int* __restrict__ bsum, unsigned int* __restrict__ boff,
    int nblocks) {
  const int t = threadIdx.x;
  unsigned int v = (t < nblocks) ? bsum[t] : 0u;
  unsigned int inc = v;
  #pragma unroll
  for (int off = 1; off < 64; off <<= 1) {
    unsigned int u = __shfl_up(inc, off);
    if (t >= off) inc += u;
  }
  if (t < nblocks) boff[t] = inc - v;
}

// K4c: add block offsets; init cursor
__global__ __launch_bounds__(1024) void k_scan3(
    unsigned int* __restrict__ start, const unsigned int* __restrict__ boff,
    unsigned int* __restrict__ cursor) {
  const int gid = blockIdx.x * 1024 + threadIdx.x;
  if (gid >= N_NODES) return;
  unsigned int s = start[gid] + boff[blockIdx.x];
  start[gid] = s; cursor[gid] = s;
}

// K5: edge logits + CSR scatter, 4 edges per thread (independent chains).
// Edge k for this thread: blockIdx.x*1024 + k*256 + threadIdx.x  (each of the
// 4 load groups stays lane-coalesced).
__global__ __launch_bounds__(256) void k_scatter(
    const int* __restrict__ ei, const float* __restrict__ eattr,
    const float* __restrict__ a_src, const float* __restrict__ a_dst,
    const float* __restrict__ W_edge, unsigned int* __restrict__ cursor,
    float4* __restrict__ rec) {
  __shared__ float We[HEADS][EDGE_DIM];
  if (threadIdx.x < HEADS * EDGE_DIM)
    ((float*)We)[threadIdx.x] = W_edge[threadIdx.x];
  __syncthreads();

  int e[4], src[4], dst[4];
  bool ok[4];
  #pragma unroll
  for (int k = 0; k < 4; ++k) {
    e[k] = blockIdx.x * 1024 + k * 256 + threadIdx.x;
    ok[k] = (e[k] < N_EDGES);
    src[k] = ok[k] ? ei[e[k]] : 0;
    dst[k] = ok[k] ? ei[N_EDGES + e[k]] : 0;
  }
  float4 as[4], ad[4];
  #pragma unroll
  for (int k = 0; k < 4; ++k) {
    as[k] = *(const float4*)(a_src + (size_t)src[k] * 4);
    ad[k] = *(const float4*)(a_dst + (size_t)dst[k] * 4);
  }
  float4 ea[4][4];
  #pragma unroll
  for (int k = 0; k < 4; ++k) {
    #pragma unroll
    for (int j = 0; j < 4; ++j)
      ea[k][j] = ok[k] ? *(const float4*)(eattr + (size_t)e[k] * EDGE_DIM + j*4)
                       : make_float4(0.f,0.f,0.f,0.f);
  }
  #pragma unroll
  for (int k = 0; k < 4; ++k) {
    if (!ok[k]) continue;
    const float* asp = (const float*)&as[k];
    const float* adp = (const float*)&ad[k];
    float lg[HEADS];
    #pragma unroll
    for (int hh = 0; hh < HEADS; ++hh) {
      float sum = asp[hh] + adp[hh];
      const float* eap = (const float*)&ea[k][0];
      #pragma unroll
      for (int j = 0; j < EDGE_DIM; ++j) sum += eap[j] * We[hh][j];
      lg[hh] = (sum > 0.f) ? sum : 0.2f * sum;
    }
    __half2 p01 = __floats2half2_rn(lg[0], lg[1]);
    __half2 p23 = __floats2half2_rn(lg[2], lg[3]);
    float4 r;
    r.x = __uint_as_float(*(const unsigned int*)&p01);
    r.y = __uint_as_float(*(const unsigned int*)&p23);
    r.z = __int_as_float(src[k]);
    r.w = 0.f;
    unsigned int pos = atomicAdd(&cursor[dst[k]], 1u);
    rec[pos] = r;
  }
}

// K6: one wave per dst, single pass, 2-deep pipelined record processing.
__global__ __launch_bounds__(256) void k_agg(
    const unsigned int* __restrict__ start, const unsigned int* __restrict__ cnt,
    const float4* __restrict__ rec, const __half* __restrict__ h2t,
    const float* __restrict__ bias, float* __restrict__ out) {
  int wid = (blockIdx.x * 256 + threadIdx.x) >> 6;
  if (wid >= N_NODES) return;
  const int lane = threadIdx.x & 63;
  const int half_ = lane >> 5, dd = lane & 31;
  const unsigned int s0 = start[wid];
  const unsigned int c = cnt[wid];

  float acc0 = 0.f, acc1 = 0.f, acc2 = 0.f, acc3 = 0.f;
  float dn0 = 0.f, dn1 = 0.f, dn2 = 0.f, dn3 = 0.f;

  unsigned int j = half_;
  // paired iterations: two records in flight per half-wave
  for (; j + 2 < c; j += 4) {
    float4 ra = rec[s0 + j];
    float4 rb = rec[s0 + j + 2];
    unsigned int a01 = __float_as_uint(ra.x), a23 = __float_as_uint(ra.y);
    unsigned int b01 = __float_as_uint(rb.x), b23 = __float_as_uint(rb.y);
    int sa = __float_as_int(ra.z), sb = __float_as_int(rb.z);
    uint2 hra = *(const uint2*)(h2t + (size_t)sa * IN_DIM + dd * 4);
    uint2 hrb = *(const uint2*)(h2t + (size_t)sb * IN_DIM + dd * 4);
    float2 la01 = __half22float2(*(const __half2*)&a01);
    float2 la23 = __half22float2(*(const __half2*)&a23);
    float pa0 = __expf(la01.x), pa1 = __expf(la01.y);
    float pa2 = __expf(la23.x), pa3 = __expf(la23.y);
    dn0 += pa0; dn1 += pa1; dn2 += pa2; dn3 += pa3;
    float2 ha01 = __half22float2(*(const __half2*)&hra.x);
    float2 ha23 = __half22float2(*(const __half2*)&hra.y);
    acc0 += pa0 * ha01.x; acc1 += pa1 * ha01.y;
    acc2 += pa2 * ha23.x; acc3 += pa3 * ha23.y;
    float2 lb01 = __half22float2(*(const __half2*)&b01);
    float2 lb23 = __half22float2(*(const __half2*)&b23);
    float pb0 = __expf(lb01.x), pb1 = __expf(lb01.y);
    float pb2 = __expf(lb23.x), pb3 = __expf(lb23.y);
    dn0 += pb0; dn1 += pb1; dn2 += pb2; dn3 += pb3;
    float2 hb01 = __half22float2(*(const __half2*)&hrb.x);
    float2 hb23 = __half22float2(*(const __half2*)&hrb.y);
    acc0 += pb0 * hb01.x; acc1 += pb1 * hb01.y;
    acc2 += pb2 * hb23.x; acc3 += pb3 * hb23.y;
  }
  for (; j < c; j += 2) {
    float4 r = rec[s0 + j];
    unsigned int u01 = __float_as_uint(r.x), u23 = __float_as_uint(r.y);
    int src = __float_as_int(r.z);
    uint2 raw = *(const uint2*)(h2t + (size_t)src * IN_DIM + dd * 4);
    float2 l01 = __half22float2(*(const __half2*)&u01);
    float2 l23 = __half22float2(*(const __half2*)&u23);
    float p0 = __expf(l01.x), p1 = __expf(l01.y);
    float p2 = __expf(l23.x), p3 = __expf(l23.y);
    dn0 += p0; dn1 += p1; dn2 += p2; dn3 += p3;
    float2 h01 = __half22float2(*(const __half2*)&raw.x);
    float2 h23 = __half22float2(*(const __half2*)&raw.y);
    acc0 += p0 * h01.x; acc1 += p1 * h01.y;
    acc2 += p2 * h23.x; acc3 += p3 * h23.y;
  }

  dn0 += __shfl_xor(dn0, 32); dn1 += __shfl_xor(dn1, 32);
  dn2 += __shfl_xor(dn2, 32); dn3 += __shfl_xor(dn3, 32);
  acc0 += __shfl_xor(acc0, 32); acc1 += __shfl_xor(acc1, 32);
  acc2 += __shfl_xor(acc2, 32); acc3 += __shfl_xor(acc3, 32);

  if (half_ == 0) {
    float v = acc0 * (0.25f / (dn0 + 1e-16f)) + acc1 * (0.25f / (dn1 + 1e-16f))
            + acc2 * (0.25f / (dn2 + 1e-16f)) + acc3 * (0.25f / (dn3 + 1e-16f));
    out[(size_t)wid * OUT_DIM + dd] = v + bias[dd];
  }
}

extern "C" void kernel_launch(void* const* d_in, const int* in_sizes, int n_in,
                              void* d_out, int out_size, void* d_ws, size_t ws_size,
                              hipStream_t stream) {
  const float* x       = (const float*)d_in[0];
  const int*   ei      = (const int*)d_in[1];
  const float* eattr   = (const float*)d_in[2];
  const float* W_lin   = (const float*)d_in[3];
  const float* att_src = (const float*)d_in[4];
  const float* att_dst = (const float*)d_in[5];
  const float* bias    = (const float*)d_in[6];
  const float* W_edge  = (const float*)d_in[7];
  float* out = (float*)d_out;

  // ws layout: h2t(fp16) | rec(16B/edge) | a_src | a_dst | cnt | start | cursor | bsum | boff
  __half* h2t  = (__half*)d_ws;                                  // 12.8 MB
  float4* rec  = (float4*)(h2t + (size_t)N_NODES * IN_DIM);      // 25.6 MB
  float* a_src = (float*)(rec + (size_t)N_EDGES);
  float* a_dst = a_src + (size_t)N_NODES * HEADS;
  unsigned int* cnt    = (unsigned int*)(a_dst + (size_t)N_NODES * HEADS);
  unsigned int* startv = cnt + N_NODES;
  unsigned int* cursor = startv + N_NODES;
  unsigned int* bsum   = cursor + N_NODES;
  unsigned int* boff   = bsum + 64;

  const int SCAN_BLOCKS = (N_NODES + 1023) / 1024;   // 49

  // zero a_src | a_dst | cnt (contiguous, 1.8 MB)
  hipMemsetAsync(a_src, 0, (size_t)N_NODES * (HEADS * 2 + 1) * sizeof(float), stream);

  k_main1<<<GEMM_BLOCKS + HIST_BLOCKS, 256, 0, stream>>>(
      x, W_lin, att_src, att_dst, ei, h2t, a_src, a_dst, cnt);
  k_scan1<<<SCAN_BLOCKS, 1024, 0, stream>>>(cnt, startv, bsum);
  k_scan2<<<1, 64, 0, stream>>>(bsum, boff, SCAN_BLOCKS);
  k_scan3<<<SCAN_BLOCKS, 1024, 0, stream>>>(startv, boff, cursor);
  k_scatter<<<(N_EDGES + 1023) / 1024, 256, 0, stream>>>(
      ei, eattr, a_src, a_dst, W_edge, cursor, rec);
  k_agg<<<(N_NODES * 64 + 255) / 256, 256, 0, stream>>>(startv, cnt, rec, h2t, bias, out);
}

// Round 5
// 303.315 us; speedup vs baseline: 1.5475x; 1.5475x over previous
//
#include <hip/hip_runtime.h>
#include <hip/hip_fp16.h>

#define N_NODES 50000
#define N_EDGES 1600000
#define IN_DIM  128
#define OUT_DIM 32
#define HEADS   4
#define EDGE_DIM 16

// K1: h = x @ W^T (32-node tile); epilogue computes a_src/a_dst via
// wave-shuffle reduction (NO global atomics) and emits fp16 transposed
// h2t[n][d][head]. f32 h is never materialized.
__global__ __launch_bounds__(256) void k_gemm(
    const float* __restrict__ x, const float* __restrict__ Wl,
    const float* __restrict__ att_src, const float* __restrict__ att_dst,
    __half* __restrict__ h2t, float* __restrict__ a_src,
    float* __restrict__ a_dst) {
  __shared__ float Wt[IN_DIM][68];
  __shared__ float xs[32][132];
  __shared__ float attS[IN_DIM], attD[IN_DIM];
  __shared__ float sred_s[32][4], sred_d[32][4];
  const int t = threadIdx.x;
  const int n0 = blockIdx.x * 32;

  if (t < IN_DIM) { attS[t] = att_src[t]; attD[t] = att_dst[t]; }

  for (int it = 0; it < 16; ++it) {
    int idx = it * 256 + t;
    int node = idx >> 7, i = idx & 127;
    int n = n0 + node;
    xs[node][i] = (n < N_NODES) ? x[(size_t)n * IN_DIM + i] : 0.f;
  }

  const int tx = t & 15, ty = t >> 4;
  const int na = n0 + 2 * ty, nb = na + 1;

  for (int p = 0; p < 2; ++p) {
    __syncthreads();
    for (int it = 0; it < 32; ++it) {
      int idx = it * 256 + t;
      int kg = (idx >> 7) + p * 64, i = idx & 127;
      Wt[i][kg - p * 64] = Wl[(size_t)kg * IN_DIM + i];
    }
    __syncthreads();

    float4 acc0 = {0.f,0.f,0.f,0.f}, acc1 = {0.f,0.f,0.f,0.f};
    for (int i4 = 0; i4 < IN_DIM; i4 += 4) {
      float4 xa = *(const float4*)&xs[2*ty][i4];
      float4 xb = *(const float4*)&xs[2*ty+1][i4];
      const float* xap = (const float*)&xa;
      const float* xbp = (const float*)&xb;
      #pragma unroll
      for (int ii = 0; ii < 4; ++ii) {
        float4 wv = *(const float4*)&Wt[i4+ii][tx*4];
        float a = xap[ii], b = xbp[ii];
        acc0.x += a*wv.x; acc0.y += a*wv.y; acc0.z += a*wv.z; acc0.w += a*wv.w;
        acc1.x += b*wv.x; acc1.y += b*wv.y; acc1.z += b*wv.z; acc1.w += b*wv.w;
      }
    }
    const int k = p*64 + tx*4;
    const int hd = k >> 5, d0 = k & 31;
    const float* ap = (const float*)&acc0;
    const float* bp = (const float*)&acc1;

    // partial attention dots over this thread's 4 k's
    float sa = ap[0]*attS[k] + ap[1]*attS[k+1] + ap[2]*attS[k+2] + ap[3]*attS[k+3];
    float da = ap[0]*attD[k] + ap[1]*attD[k+1] + ap[2]*attD[k+2] + ap[3]*attD[k+3];
    float sb = bp[0]*attS[k] + bp[1]*attS[k+1] + bp[2]*attS[k+2] + bp[3]*attS[k+3];
    float db = bp[0]*attD[k] + bp[1]*attD[k+1] + bp[2]*attD[k+2] + bp[3]*attD[k+3];
    // reduce across the 8 tx-lanes sharing (node, head): lanes tx&7
    #pragma unroll
    for (int off = 1; off <= 4; off <<= 1) {
      sa += __shfl_xor(sa, off); da += __shfl_xor(da, off);
      sb += __shfl_xor(sb, off); db += __shfl_xor(db, off);
    }
    if ((tx & 7) == 0) {
      sred_s[2*ty][hd] = sa; sred_s[2*ty+1][hd] = sb;
      sred_d[2*ty][hd] = da; sred_d[2*ty+1][hd] = db;
    }

    if (na < N_NODES) {
      #pragma unroll
      for (int j = 0; j < 4; ++j)
        h2t[(size_t)na*IN_DIM + (d0+j)*4 + hd] = __float2half(ap[j]);
    }
    if (nb < N_NODES) {
      #pragma unroll
      for (int j = 0; j < 4; ++j)
        h2t[(size_t)nb*IN_DIM + (d0+j)*4 + hd] = __float2half(bp[j]);
    }
  }
  __syncthreads();
  // coalesced flush: 128 floats each for a_src / a_dst
  if (t < 128) {
    int node = t >> 2;
    if (n0 + node < N_NODES)
      a_src[(size_t)(n0 + node) * 4 + (t & 3)] = sred_s[node][t & 3];
  } else {
    int tt = t - 128, node = tt >> 2;
    if (n0 + node < N_NODES)
      a_dst[(size_t)(n0 + node) * 4 + (tt & 3)] = sred_d[node][tt & 3];
  }
}

// K2: degree histogram over dst
__global__ __launch_bounds__(256) void k_hist(
    const int* __restrict__ ei, unsigned int* __restrict__ cnt) {
  int e = blockIdx.x * 256 + threadIdx.x;
  if (e >= N_EDGES) return;
  atomicAdd(&cnt[ei[N_EDGES + e]], 1u);
}

// K3a: per-block exclusive scan (1024 entries/block) + block totals
__global__ __launch_bounds__(1024) void k_scan1(
    const unsigned int* __restrict__ cnt, unsigned int* __restrict__ start,
    unsigned int* __restrict__ bsum) {
  __shared__ unsigned int s[1024];
  const int t = threadIdx.x;
  const int gid = blockIdx.x * 1024 + t;
  unsigned int v = (gid < N_NODES) ? cnt[gid] : 0u;
  s[t] = v; __syncthreads();
  for (int off = 1; off < 1024; off <<= 1) {
    unsigned int u = (t >= off) ? s[t - off] : 0u;
    __syncthreads();
    s[t] += u;
    __syncthreads();
  }
  if (gid < N_NODES) start[gid] = s[t] - v;
  if (t == 1023) bsum[blockIdx.x] = s[t];
}

// K3b: scan the 49 block totals (single wave)
__global__ __launch_bounds__(64) void k_scan2(
    const unsigned int* __restrict__ bsum, unsigned int* __restrict__ boff,
    int nblocks) {
  const int t = threadIdx.x;
  unsigned int v = (t < nblocks) ? bsum[t] : 0u;
  unsigned int inc = v;
  #pragma unroll
  for (int off = 1; off < 64; off <<= 1) {
    unsigned int u = __shfl_up(inc, off);
    if (t >= off) inc += u;
  }
  if (t < nblocks) boff[t] = inc - v;
}

// K3c: add block offsets; init cursor
__global__ __launch_bounds__(1024) void k_scan3(
    unsigned int* __restrict__ start, const unsigned int* __restrict__ boff,
    unsigned int* __restrict__ cursor) {
  const int gid = blockIdx.x * 1024 + threadIdx.x;
  if (gid >= N_NODES) return;
  unsigned int s = start[gid] + boff[blockIdx.x];
  start[gid] = s; cursor[gid] = s;
}

// K4: edge logits + CSR scatter, 4 edges per thread (independent chains).
__global__ __launch_bounds__(256) void k_scatter(
    const int* __restrict__ ei, const float* __restrict__ eattr,
    const float* __restrict__ a_src, const float* __restrict__ a_dst,
    const float* __restrict__ W_edge, unsigned int* __restrict__ cursor,
    float4* __restrict__ rec) {
  __shared__ float We[HEADS][EDGE_DIM];
  if (threadIdx.x < HEADS * EDGE_DIM)
    ((float*)We)[threadIdx.x] = W_edge[threadIdx.x];
  __syncthreads();

  int e[4], src[4], dst[4];
  bool ok[4];
  #pragma unroll
  for (int k = 0; k < 4; ++k) {
    e[k] = blockIdx.x * 1024 + k * 256 + threadIdx.x;
    ok[k] = (e[k] < N_EDGES);
    src[k] = ok[k] ? ei[e[k]] : 0;
    dst[k] = ok[k] ? ei[N_EDGES + e[k]] : 0;
  }
  float4 as[4], ad[4];
  #pragma unroll
  for (int k = 0; k < 4; ++k) {
    as[k] = *(const float4*)(a_src + (size_t)src[k] * 4);
    ad[k] = *(const float4*)(a_dst + (size_t)dst[k] * 4);
  }
  float4 ea[4][4];
  #pragma unroll
  for (int k = 0; k < 4; ++k) {
    #pragma unroll
    for (int j = 0; j < 4; ++j)
      ea[k][j] = ok[k] ? *(const float4*)(eattr + (size_t)e[k] * EDGE_DIM + j*4)
                       : make_float4(0.f,0.f,0.f,0.f);
  }
  #pragma unroll
  for (int k = 0; k < 4; ++k) {
    if (!ok[k]) continue;
    const float* asp = (const float*)&as[k];
    const float* adp = (const float*)&ad[k];
    float lg[HEADS];
    #pragma unroll
    for (int hh = 0; hh < HEADS; ++hh) {
      float sum = asp[hh] + adp[hh];
      const float* eap = (const float*)&ea[k][0];
      #pragma unroll
      for (int j = 0; j < EDGE_DIM; ++j) sum += eap[j] * We[hh][j];
      lg[hh] = (sum > 0.f) ? sum : 0.2f * sum;
    }
    __half2 p01 = __floats2half2_rn(lg[0], lg[1]);
    __half2 p23 = __floats2half2_rn(lg[2], lg[3]);
    float4 r;
    r.x = __uint_as_float(*(const unsigned int*)&p01);
    r.y = __uint_as_float(*(const unsigned int*)&p23);
    r.z = __int_as_float(src[k]);
    r.w = 0.f;
    unsigned int pos = atomicAdd(&cursor[dst[k]], 1u);
    rec[pos] = r;
  }
}

// K5: one wave per dst, single pass, 2-deep pipelined record processing.
__global__ __launch_bounds__(256) void k_agg(
    const unsigned int* __restrict__ start, const unsigned int* __restrict__ cnt,
    const float4* __restrict__ rec, const __half* __restrict__ h2t,
    const float* __restrict__ bias, float* __restrict__ out) {
  int wid = (blockIdx.x * 256 + threadIdx.x) >> 6;
  if (wid >= N_NODES) return;
  const int lane = threadIdx.x & 63;
  const int half_ = lane >> 5, dd = lane & 31;
  const unsigned int s0 = start[wid];
  const unsigned int c = cnt[wid];

  float acc0 = 0.f, acc1 = 0.f, acc2 = 0.f, acc3 = 0.f;
  float dn0 = 0.f, dn1 = 0.f, dn2 = 0.f, dn3 = 0.f;

  unsigned int j = half_;
  for (; j + 2 < c; j += 4) {
    float4 ra = rec[s0 + j];
    float4 rb = rec[s0 + j + 2];
    unsigned int a01 = __float_as_uint(ra.x), a23 = __float_as_uint(ra.y);
    unsigned int b01 = __float_as_uint(rb.x), b23 = __float_as_uint(rb.y);
    int sa = __float_as_int(ra.z), sb = __float_as_int(rb.z);
    uint2 hra = *(const uint2*)(h2t + (size_t)sa * IN_DIM + dd * 4);
    uint2 hrb = *(const uint2*)(h2t + (size_t)sb * IN_DIM + dd * 4);
    float2 la01 = __half22float2(*(const __half2*)&a01);
    float2 la23 = __half22float2(*(const __half2*)&a23);
    float pa0 = __expf(la01.x), pa1 = __expf(la01.y);
    float pa2 = __expf(la23.x), pa3 = __expf(la23.y);
    dn0 += pa0; dn1 += pa1; dn2 += pa2; dn3 += pa3;
    float2 ha01 = __half22float2(*(const __half2*)&hra.x);
    float2 ha23 = __half22float2(*(const __half2*)&hra.y);
    acc0 += pa0 * ha01.x; acc1 += pa1 * ha01.y;
    acc2 += pa2 * ha23.x; acc3 += pa3 * ha23.y;
    float2 lb01 = __half22float2(*(const __half2*)&b01);
    float2 lb23 = __half22float2(*(const __half2*)&b23);
    float pb0 = __expf(lb01.x), pb1 = __expf(lb01.y);
    float pb2 = __expf(lb23.x), pb3 = __expf(lb23.y);
    dn0 += pb0; dn1 += pb1; dn2 += pb2; dn3 += pb3;
    float2 hb01 = __half22float2(*(const __half2*)&hrb.x);
    float2 hb23 = __half22float2(*(const __half2*)&hrb.y);
    acc0 += pb0 * hb01.x; acc1 += pb1 * hb01.y;
    acc2 += pb2 * hb23.x; acc3 += pb3 * hb23.y;
  }
  for (; j < c; j += 2) {
    float4 r = rec[s0 + j];
    unsigned int u01 = __float_as_uint(r.x), u23 = __float_as_uint(r.y);
    int src = __float_as_int(r.z);
    uint2 raw = *(const uint2*)(h2t + (size_t)src * IN_DIM + dd * 4);
    float2 l01 = __half22float2(*(const __half2*)&u01);
    float2 l23 = __half22float2(*(const __half2*)&u23);
    float p0 = __expf(l01.x), p1 = __expf(l01.y);
    float p2 = __expf(l23.x), p3 = __expf(l23.y);
    dn0 += p0; dn1 += p1; dn2 += p2; dn3 += p3;
    float2 h01 = __half22float2(*(const __half2*)&raw.x);
    float2 h23 = __half22float2(*(const __half2*)&raw.y);
    acc0 += p0 * h01.x; acc1 += p1 * h01.y;
    acc2 += p2 * h23.x; acc3 += p3 * h23.y;
  }

  dn0 += __shfl_xor(dn0, 32); dn1 += __shfl_xor(dn1, 32);
  dn2 += __shfl_xor(dn2, 32); dn3 += __shfl_xor(dn3, 32);
  acc0 += __shfl_xor(acc0, 32); acc1 += __shfl_xor(acc1, 32);
  acc2 += __shfl_xor(acc2, 32); acc3 += __shfl_xor(acc3, 32);

  if (half_ == 0) {
    float v = acc0 * (0.25f / (dn0 + 1e-16f)) + acc1 * (0.25f / (dn1 + 1e-16f))
            + acc2 * (0.25f / (dn2 + 1e-16f)) + acc3 * (0.25f / (dn3 + 1e-16f));
    out[(size_t)wid * OUT_DIM + dd] = v + bias[dd];
  }
}

extern "C" void kernel_launch(void* const* d_in, const int* in_sizes, int n_in,
                              void* d_out, int out_size, void* d_ws, size_t ws_size,
                              hipStream_t stream) {
  const float* x       = (const float*)d_in[0];
  const int*   ei      = (const int*)d_in[1];
  const float* eattr   = (const float*)d_in[2];
  const float* W_lin   = (const float*)d_in[3];
  const float* att_src = (const float*)d_in[4];
  const float* att_dst = (const float*)d_in[5];
  const float* bias    = (const float*)d_in[6];
  const float* W_edge  = (const float*)d_in[7];
  float* out = (float*)d_out;

  // ws layout: h2t(fp16) | rec(16B/edge) | a_src | a_dst | cnt | start | cursor | bsum | boff
  __half* h2t  = (__half*)d_ws;                                  // 12.8 MB
  float4* rec  = (float4*)(h2t + (size_t)N_NODES * IN_DIM);      // 25.6 MB
  float* a_src = (float*)(rec + (size_t)N_EDGES);
  float* a_dst = a_src + (size_t)N_NODES * HEADS;
  unsigned int* cnt    = (unsigned int*)(a_dst + (size_t)N_NODES * HEADS);
  unsigned int* startv = cnt + N_NODES;
  unsigned int* cursor = startv + N_NODES;
  unsigned int* bsum   = cursor + N_NODES;
  unsigned int* boff   = bsum + 64;

  const int SCAN_BLOCKS = (N_NODES + 1023) / 1024;   // 49

  hipMemsetAsync(cnt, 0, (size_t)N_NODES * sizeof(unsigned int), stream);

  k_gemm<<<(N_NODES + 31) / 32, 256, 0, stream>>>(
      x, W_lin, att_src, att_dst, h2t, a_src, a_dst);
  k_hist<<<(N_EDGES + 255) / 256, 256, 0, stream>>>(ei, cnt);
  k_scan1<<<SCAN_BLOCKS, 1024, 0, stream>>>(cnt, startv, bsum);
  k_scan2<<<1, 64, 0, stream>>>(bsum, boff, SCAN_BLOCKS);
  k_scan3<<<SCAN_BLOCKS, 1024, 0, stream>>>(startv, boff, cursor);
  k_scatter<<<(N_EDGES + 1023) / 1024, 256, 0, stream>>>(
      ei, eattr, a_src, a_dst, W_edge, cursor, rec);
  k_agg<<<(N_NODES * 64 + 255) / 256, 256, 0, stream>>>(startv, cnt, rec, h2t, bias, out);
}